// Round 4
// baseline (605.915 us; speedup 1.0000x reference)
//
#include <hip/hip_runtime.h>

typedef __attribute__((ext_vector_type(8))) short short8;
typedef __attribute__((ext_vector_type(4))) float float4v;

#define V_ 20000
#define KS 32         // split-K slices

__device__ __forceinline__ unsigned short f2bf(float f) {
    union { float f; unsigned int u; } v; v.f = f;
    unsigned int u = v.u;
    u += 0x7fffu + ((u >> 16) & 1u);
    return (unsigned short)(u >> 16);
}

__device__ __forceinline__ float fast_tanh(float x) {
    float xc = fminf(15.f, fmaxf(-15.f, x));
    float e = __expf(2.f * xc);
    return (e - 1.f) / (e + 1.f);   // tanh(0) == 0 exactly (mask depends on it)
}

__device__ __forceinline__ float sigmoidf_(float x) {
    float xc = fminf(30.f, fmaxf(-30.f, x));
    return 1.f / (1.f + __expf(-xc));
}

// ---------------------------------------------------------------- cvt emb -> bf16 transposed [128n][20000k]
__global__ __launch_bounds__(256) void cvt_embT(const float* __restrict__ emb,
                                                unsigned short* __restrict__ embT) {
    __shared__ unsigned short tile[128 * 65];
    int tid = threadIdx.x;
    int k0 = blockIdx.x * 64;
    const float4v* e4 = (const float4v*)emb;
    #pragma unroll
    for (int c = 0; c < 8; ++c) {
        int l4 = c * 256 + tid;      // float4 index in 64k x 128n tile
        int k = l4 >> 5;             // 32 float4 per k-row
        int n4 = l4 & 31;
        float4v f = {0.f, 0.f, 0.f, 0.f};
        if (k0 + k < V_) f = e4[(size_t)(k0 + k) * 32 + n4];
        tile[(n4 * 4 + 0) * 65 + k] = f2bf(f.x);
        tile[(n4 * 4 + 1) * 65 + k] = f2bf(f.y);
        tile[(n4 * 4 + 2) * 65 + k] = f2bf(f.z);
        tile[(n4 * 4 + 3) * 65 + k] = f2bf(f.w);
    }
    __syncthreads();
    #pragma unroll
    for (int c = 0; c < 4; ++c) {
        int l8 = c * 256 + tid;      // n*8 + seg
        int n = l8 >> 3, seg = l8 & 7;
        int kk = k0 + seg * 8;
        if (kk < V_) {
            short8 v;
            #pragma unroll
            for (int i = 0; i < 8; ++i) v[i] = (short)tile[n * 65 + seg * 8 + i];
            *(short8*)(embT + (size_t)n * V_ + kk) = v;
        }
    }
}

// ---------------------------------------------------------------- big GEMM: partial[KS][3232][128]
// Barrier-free / LDS-free: each wave owns a 32-row x 128-col tile and a K-slice.
// A: global fp32 -> reg -> bf16 (prefetched one K-step ahead). B: inline from
// L1/L2-resident embT. Only dependency inside the K-loop is the accumulator.
__global__ __launch_bounds__(256, 3) void big_gemm(const float* __restrict__ x,
                                                   const float* __restrict__ a,
                                                   const unsigned short* __restrict__ embT,
                                                   float* __restrict__ partial) {
    int tid = threadIdx.x;
    int w = tid >> 6, lane = tid & 63;
    int ln = lane & 15, quad = lane >> 4;
    int tile = blockIdx.x * 4 + w;       // 32-row tile index, 0..103
    if (tile > 100) return;              // tiles 101..103: no rows
    int by = blockIdx.y;                 // k-slice
    int r0 = tile * 32;

    // 625 k-blocks (of 32) over KS=32 slices: 19 each, first 17 get +1
    int kb0 = by * 19 + (by < 17 ? by : 17);
    int cnt = 19 + (by < 17 ? 1 : 0);

    const float* __restrict__ src0;
    const float* __restrict__ src1;
    if (r0 < 3200) {
        src0 = x + (size_t)(r0 + ln) * V_;
        src1 = x + (size_t)(r0 + 16 + ln) * V_;
    } else {                             // tile 100 == the 32 'a' rows
        src0 = a + (size_t)ln * V_;
        src1 = a + (size_t)(16 + ln) * V_;
    }
    const unsigned short* __restrict__ bp0 = embT + (size_t)ln * V_ + quad * 8;

    float4v acc[2][8];
    #pragma unroll
    for (int f = 0; f < 2; ++f)
        #pragma unroll
        for (int t = 0; t < 8; ++t) acc[f][t] = (float4v){0.f, 0.f, 0.f, 0.f};

    int kq = kb0 * 32 + quad * 8;
    // prefetch A for step 0
    float4v a00 = *(const float4v*)(src0 + kq);
    float4v a01 = *(const float4v*)(src0 + kq + 4);
    float4v a10 = *(const float4v*)(src1 + kq);
    float4v a11 = *(const float4v*)(src1 + kq + 4);

    for (int s = 0; s < cnt; ++s) {
        int k = (kb0 + s) * 32;
        float4v n00, n01, n10, n11;
        if (s + 1 < cnt) {
            int knq = k + 32 + quad * 8;
            n00 = *(const float4v*)(src0 + knq);
            n01 = *(const float4v*)(src0 + knq + 4);
            n10 = *(const float4v*)(src1 + knq);
            n11 = *(const float4v*)(src1 + knq + 4);
        }
        // B fragments for this K-step (8 col-tiles)
        short8 bf[8];
        #pragma unroll
        for (int t = 0; t < 8; ++t)
            bf[t] = *(const short8*)(bp0 + (size_t)t * 16 * V_ + k);
        // convert prefetched A to bf16 fragments
        short8 pa0, pa1;
        pa0[0]=(short)f2bf(a00.x); pa0[1]=(short)f2bf(a00.y); pa0[2]=(short)f2bf(a00.z); pa0[3]=(short)f2bf(a00.w);
        pa0[4]=(short)f2bf(a01.x); pa0[5]=(short)f2bf(a01.y); pa0[6]=(short)f2bf(a01.z); pa0[7]=(short)f2bf(a01.w);
        pa1[0]=(short)f2bf(a10.x); pa1[1]=(short)f2bf(a10.y); pa1[2]=(short)f2bf(a10.z); pa1[3]=(short)f2bf(a10.w);
        pa1[4]=(short)f2bf(a11.x); pa1[5]=(short)f2bf(a11.y); pa1[6]=(short)f2bf(a11.z); pa1[7]=(short)f2bf(a11.w);
        #pragma unroll
        for (int t = 0; t < 8; ++t) {
            acc[0][t] = __builtin_amdgcn_mfma_f32_16x16x32_bf16(pa0, bf[t], acc[0][t], 0, 0, 0);
            acc[1][t] = __builtin_amdgcn_mfma_f32_16x16x32_bf16(pa1, bf[t], acc[1][t], 0, 0, 0);
        }
        a00 = n00; a01 = n01; a10 = n10; a11 = n11;
    }

    // epilogue: C[row = r0 + f*16 + quad*4 + reg][col = t*16 + ln]
    float* dst = partial + ((size_t)by * 3232 + r0 + quad * 4) * 128 + ln;
    #pragma unroll
    for (int f = 0; f < 2; ++f) {
        #pragma unroll
        for (int t = 0; t < 8; ++t) {
            #pragma unroll
            for (int reg = 0; reg < 4; ++reg)
                dst[(size_t)(f * 16 + reg) * 128 + t * 16] = acc[f][t][reg];
        }
    }
}

// ---------------------------------------------------------------- reduce K-slices + tanh + mask
__global__ __launch_bounds__(128) void reduce_tanh(const float* __restrict__ partial,
                                                   float* __restrict__ xe,
                                                   float* __restrict__ ae,
                                                   float* __restrict__ maskg) {
    int row = blockIdx.x;   // 0..3231
    int e = threadIdx.x;
    float s = 0.f;
    #pragma unroll
    for (int k = 0; k < KS; ++k)
        s += partial[((size_t)k * 3232 + row) * 128 + e];
    float v = fast_tanh(s);
    if (row < 3200) {
        xe[(size_t)row * 128 + e] = v;
        __shared__ int any;
        if (e == 0) any = 0;
        __syncthreads();
        if (v != 0.f) any = 1;
        __syncthreads();
        if (e == 0) maskg[row] = any ? 1.f : 0.f;
    } else {
        ae[(row - 3200) * 128 + e] = v;
    }
}

// ---------------------------------------------------------------- x_proj = xe @ gru_k + b_i   [3200][384]
__global__ __launch_bounds__(384) void xproj_kernel(const float* __restrict__ xe,
                                                    const float* __restrict__ gru_k,
                                                    const float* __restrict__ b_i,
                                                    float* __restrict__ xproj) {
    __shared__ float xs[16 * 128];
    int tid = threadIdx.x;
    int row0 = blockIdx.x * 16;
    const float4v* src = (const float4v*)(xe + (size_t)row0 * 128);
    float4v* dstl = (float4v*)xs;
    #pragma unroll
    for (int c = 0; c < 2; ++c) {
        int i4 = c * 384 + tid;
        if (i4 < 512) dstl[i4] = src[i4];
    }
    __syncthreads();
    int j = tid;  // 0..383
    float acc[16];
    #pragma unroll
    for (int r = 0; r < 16; ++r) acc[r] = 0.f;
    float bi = b_i[j];
    for (int k4 = 0; k4 < 32; ++k4) {
        float g0 = gru_k[(k4 * 4 + 0) * 384 + j];
        float g1 = gru_k[(k4 * 4 + 1) * 384 + j];
        float g2 = gru_k[(k4 * 4 + 2) * 384 + j];
        float g3 = gru_k[(k4 * 4 + 3) * 384 + j];
        #pragma unroll
        for (int r = 0; r < 16; ++r) {
            float4v xv = *(const float4v*)&xs[r * 128 + k4 * 4];
            acc[r] = fmaf(xv.x, g0, acc[r]);
            acc[r] = fmaf(xv.y, g1, acc[r]);
            acc[r] = fmaf(xv.z, g2, acc[r]);
            acc[r] = fmaf(xv.w, g3, acc[r]);
        }
    }
    #pragma unroll
    for (int r = 0; r < 16; ++r)
        xproj[(size_t)(row0 + r) * 384 + j] = acc[r] + bi;
}

// ---------------------------------------------------------------- GRU scan: 1 block / batch
__global__ __launch_bounds__(384) void gru_kernel(const float* __restrict__ xproj,
                                                  const float* __restrict__ maskg,
                                                  const float* __restrict__ gru_rk,
                                                  const float* __restrict__ b_r,
                                                  float* __restrict__ hout) {
    int b = blockIdx.x;
    int j = threadIdx.x;  // 0..383
    float w[128];
    #pragma unroll
    for (int k = 0; k < 128; ++k) w[k] = gru_rk[k * 384 + j];
    float br = b_r[j];
    __shared__ float4v hs4[32];
    __shared__ float recs[384];
    float* hs = (float*)hs4;
    float hreg = 0.f;
    if (j < 128) hs[j] = 0.f;
    const float* xp_base = xproj + (size_t)b * 100 * 384;
    const float* mk = maskg + b * 100;
    float xz = 0.f, xr = 0.f, xh = 0.f;
    if (j < 128) { xz = xp_base[j]; xr = xp_base[128 + j]; xh = xp_base[256 + j]; }
    __syncthreads();
    for (int t = 0; t < 100; ++t) {
        float nxz = 0.f, nxr = 0.f, nxh = 0.f;
        if (t < 99 && j < 128) {
            const float* nb = xp_base + (t + 1) * 384;
            nxz = nb[j]; nxr = nb[128 + j]; nxh = nb[256 + j];
        }
        float s0 = 0.f, s1 = 0.f, s2 = 0.f, s3 = 0.f;
        #pragma unroll
        for (int k4 = 0; k4 < 32; ++k4) {
            float4v hv = hs4[k4];
            s0 = fmaf(hv.x, w[k4 * 4 + 0], s0);
            s1 = fmaf(hv.y, w[k4 * 4 + 1], s1);
            s2 = fmaf(hv.z, w[k4 * 4 + 2], s2);
            s3 = fmaf(hv.w, w[k4 * 4 + 3], s3);
        }
        recs[j] = br + ((s0 + s1) + (s2 + s3));
        __syncthreads();
        if (j < 128) {
            float z = sigmoidf_(xz + recs[j]);
            float r = sigmoidf_(xr + recs[128 + j]);
            float hh = fast_tanh(xh + r * recs[256 + j]);
            float hn = z * hreg + (1.f - z) * hh;
            hreg = (mk[t] != 0.f) ? hn : hreg;
            hs[j] = hreg;
        }
        __syncthreads();
        xz = nxz; xr = nxr; xh = nxh;
    }
    if (j < 128) hout[b * 128 + j] = hreg;
}

// ---------------------------------------------------------------- head
__global__ __launch_bounds__(64) void head_kernel(const float* __restrict__ hout,
                                                  const float* __restrict__ ae,
                                                  const float* __restrict__ d,
                                                  const float* __restrict__ W1,
                                                  const float* __restrict__ b1,
                                                  const float* __restrict__ W2,
                                                  const float* __restrict__ b2,
                                                  float* __restrict__ out) {
    int b = blockIdx.x;
    int m = threadIdx.x;  // 0..63
    float s = b1[m];
    const float* hb = hout + b * 128;
    const float* ab = ae + b * 128;
    #pragma unroll 4
    for (int k = 0; k < 128; ++k) s = fmaf(hb[k], W1[k * 64 + m], s);
    #pragma unroll 4
    for (int k = 0; k < 128; ++k) s = fmaf(ab[k], W1[(128 + k) * 64 + m], s);
    float c = fast_tanh(s);
    float p = c * W2[m];
    #pragma unroll
    for (int off = 32; off > 0; off >>= 1) p += __shfl_down(p, off);
    if (m == 0) {
        p += d[b * 2 + 0] * W2[64] + d[b * 2 + 1] * W2[65] + b2[0];
        out[b] = sigmoidf_(p);
    }
}

extern "C" void kernel_launch(void* const* d_in, const int* in_sizes, int n_in,
                              void* d_out, int out_size, void* d_ws, size_t ws_size,
                              hipStream_t stream) {
    (void)in_sizes; (void)n_in; (void)out_size; (void)ws_size;
    const float* x      = (const float*)d_in[0];
    const float* a      = (const float*)d_in[1];
    const float* d      = (const float*)d_in[2];
    const float* emb    = (const float*)d_in[3];
    const float* gru_k  = (const float*)d_in[4];
    const float* gru_rk = (const float*)d_in[5];
    const float* gbi    = (const float*)d_in[6];
    const float* gbr    = (const float*)d_in[7];
    const float* W1     = (const float*)d_in[8];
    const float* b1     = (const float*)d_in[9];
    const float* W2     = (const float*)d_in[10];
    const float* b2     = (const float*)d_in[11];
    float* out = (float*)d_out;

    char* ws = (char*)d_ws;
    unsigned short* embT = (unsigned short*)(ws);              //  5,120,000 B
    float* xe      = (float*)(ws + 5120000);                   //  1,638,400 B
    float* ae      = (float*)(ws + 6758400);                   //     16,384 B
    float* maskg   = (float*)(ws + 6774784);                   //     12,800 B
    float* xproj   = (float*)(ws + 6787584);                   //  4,915,200 B
    float* hout    = (float*)(ws + 11702784);                  //     16,384 B
    float* partial = (float*)(ws + 11719168);                  // 52,953,088 B (KS*3232*128*4)

    hipLaunchKernelGGL(cvt_embT,    dim3(313),      dim3(256), 0, stream, emb, embT);
    hipLaunchKernelGGL(big_gemm,    dim3(26, KS),   dim3(256), 0, stream, x, a, embT, partial);
    hipLaunchKernelGGL(reduce_tanh, dim3(3232),     dim3(128), 0, stream, partial, xe, ae, maskg);
    hipLaunchKernelGGL(xproj_kernel,dim3(200),      dim3(384), 0, stream, xe, gru_k, gbi, xproj);
    hipLaunchKernelGGL(gru_kernel,  dim3(32),       dim3(384), 0, stream, xproj, maskg, gru_rk, gbr, hout);
    hipLaunchKernelGGL(head_kernel, dim3(32),       dim3(64),  0, stream, hout, ae, d, W1, b1, W2, b2, out);
}

// Round 5
// 597.352 us; speedup vs baseline: 1.0143x; 1.0143x over previous
//
#include <hip/hip_runtime.h>

typedef __attribute__((ext_vector_type(8))) short short8;
typedef __attribute__((ext_vector_type(4))) float float4v;

#define V_ 20000
#define KS 8          // split-K slices (unit-aligned: 625 k-units of 32 floats)
#define NT 10         // 256-float tiles per slice (ceil(2528/256))
#define LSTR 264      // LDS row stride in shorts (256 + 8; keeps rows 16-B aligned)

__device__ __forceinline__ unsigned short f2bf(float f) {
    union { float f; unsigned int u; } v; v.f = f;
    unsigned int u = v.u;
    u += 0x7fffu + ((u >> 16) & 1u);
    return (unsigned short)(u >> 16);
}

__device__ __forceinline__ float fast_tanh(float x) {
    float xc = fminf(15.f, fmaxf(-15.f, x));
    float e = __expf(2.f * xc);
    return (e - 1.f) / (e + 1.f);   // tanh(0) == 0 exactly (mask depends on it)
}

__device__ __forceinline__ float sigmoidf_(float x) {
    float xc = fminf(30.f, fmaxf(-30.f, x));
    return 1.f / (1.f + __expf(-xc));
}

// ---------------------------------------------------------------- cvt emb -> bf16 transposed [128n][20000k]
__global__ __launch_bounds__(256) void cvt_embT(const float* __restrict__ emb,
                                                unsigned short* __restrict__ embT) {
    __shared__ unsigned short tile[128 * 65];
    int tid = threadIdx.x;
    int k0 = blockIdx.x * 64;
    const float4v* e4 = (const float4v*)emb;
    #pragma unroll
    for (int c = 0; c < 8; ++c) {
        int l4 = c * 256 + tid;      // float4 index in 64k x 128n tile
        int k = l4 >> 5;             // 32 float4 per k-row
        int n4 = l4 & 31;
        float4v f = {0.f, 0.f, 0.f, 0.f};
        if (k0 + k < V_) f = e4[(size_t)(k0 + k) * 32 + n4];
        tile[(n4 * 4 + 0) * 65 + k] = f2bf(f.x);
        tile[(n4 * 4 + 1) * 65 + k] = f2bf(f.y);
        tile[(n4 * 4 + 2) * 65 + k] = f2bf(f.z);
        tile[(n4 * 4 + 3) * 65 + k] = f2bf(f.w);
    }
    __syncthreads();
    #pragma unroll
    for (int c = 0; c < 4; ++c) {
        int l8 = c * 256 + tid;      // n*8 + seg
        int n = l8 >> 3, seg = l8 & 7;
        int kk = k0 + seg * 8;
        if (kk < V_) {
            short8 v;
            #pragma unroll
            for (int i = 0; i < 8; ++i) v[i] = (short)tile[n * 65 + seg * 8 + i];
            *(short8*)(embT + (size_t)n * V_ + kk) = v;
        }
    }
}

// ---------------------------------------------------------------- big GEMM: partial[KS][3232][128]
// DRAM-page-friendly: every A wave-load is 1 KB CONTIGUOUS of one x-row
// (64 lanes x float4), so each memory instruction hits 8 consecutive HBM
// lines in one page instead of spraying 16-32 pages. 16-row x 256-float
// tiles staged reg->bf16->LDS (double-buffered); each wave MFMAs a 16x32
// column slice with B from cache-resident embT.
__global__ __launch_bounds__(256) void big_gemm(const float* __restrict__ x,
                                                const float* __restrict__ a,
                                                const unsigned short* __restrict__ embT,
                                                float* __restrict__ partial) {
    __shared__ unsigned short Alds[2][16 * LSTR];
    int tid = threadIdx.x;
    int w = tid >> 6, lane = tid & 63;
    int ln = lane & 15, quad = lane >> 4;
    int bx = blockIdx.x, by = blockIdx.y;
    int r0 = bx * 16;

    // slice by: 625 k-units of 32 over KS=8 -> 79 for by==0, else 78
    int ustart = by * 78 + (by < 1 ? by : 1);
    int nu = 78 + (by < 1 ? 1 : 0);
    int kbase = ustart * 32;
    int klen = nu * 32;                    // 2528 or 2496

    // A staging pointers: wave w stages rows w, w+4, w+8, w+12 of the tile;
    // lane i covers floats [4i, 4i+4) of the 256-float chunk (contiguous 1 KB/wave-load)
    const float* srcP[4];
    #pragma unroll
    for (int j = 0; j < 4; ++j) {
        int rg = r0 + w + 4 * j;
        const float* base = (rg < 3200) ? (x + (size_t)rg * V_)
                                        : (a + (size_t)(rg - 3200) * V_);
        srcP[j] = base + kbase + lane * 4;
    }
    // B pointers: wave w covers col-tiles w*2, w*2+1
    const unsigned short* bp0 = embT + (size_t)((w * 2 + 0) * 16 + ln) * V_ + kbase + quad * 8;
    const unsigned short* bp1 = embT + (size_t)((w * 2 + 1) * 16 + ln) * V_ + kbase + quad * 8;

    float4v acc0 = {0.f, 0.f, 0.f, 0.f};
    float4v acc1 = {0.f, 0.f, 0.f, 0.f};
    float4v f0, f1, f2, f3;

    int wbr = w + 0;  // rows this wave writes: w+4j

    // prologue: load + stage tile 0 (always full 256)
    f0 = *(const float4v*)(srcP[0]);
    f1 = *(const float4v*)(srcP[1]);
    f2 = *(const float4v*)(srcP[2]);
    f3 = *(const float4v*)(srcP[3]);
    {
        unsigned short* dst = &Alds[0][lane * 4];
        unsigned short s[16];
        s[0]=f2bf(f0.x); s[1]=f2bf(f0.y); s[2]=f2bf(f0.z); s[3]=f2bf(f0.w);
        s[4]=f2bf(f1.x); s[5]=f2bf(f1.y); s[6]=f2bf(f1.z); s[7]=f2bf(f1.w);
        s[8]=f2bf(f2.x); s[9]=f2bf(f2.y); s[10]=f2bf(f2.z); s[11]=f2bf(f2.w);
        s[12]=f2bf(f3.x); s[13]=f2bf(f3.y); s[14]=f2bf(f3.z); s[15]=f2bf(f3.w);
        #pragma unroll
        for (int j = 0; j < 4; ++j) {
            int rr = wbr + 4 * j;
            *(uint2*)&dst[rr * LSTR] = *(uint2*)&s[j * 4];
        }
    }
    __syncthreads();

    for (int t = 0; t < NT; ++t) {
        int buf = t & 1;
        bool more = (t + 1 < NT);
        if (more) {
            int nlim = klen - (t + 1) * 256;             // 256 except last (224/192)
            bool ok = (lane * 4 < nlim);
            int off = (t + 1) * 256;
            float4v z = {0.f, 0.f, 0.f, 0.f};
            f0 = ok ? *(const float4v*)(srcP[0] + off) : z;
            f1 = ok ? *(const float4v*)(srcP[1] + off) : z;
            f2 = ok ? *(const float4v*)(srcP[2] + off) : z;
            f3 = ok ? *(const float4v*)(srcP[3] + off) : z;
        }
        // MFMA phase on buf
        const unsigned short* al = &Alds[buf][ln * LSTR + quad * 8];
        const unsigned short* b0p = bp0 + t * 256;
        const unsigned short* b1p = bp1 + t * 256;
        #pragma unroll
        for (int kk = 0; kk < 8; ++kk) {
            short8 af = *(const short8*)(al + kk * 32);
            short8 bf0 = *(const short8*)(b0p + kk * 32);
            short8 bf1 = *(const short8*)(b1p + kk * 32);
            acc0 = __builtin_amdgcn_mfma_f32_16x16x32_bf16(af, bf0, acc0, 0, 0, 0);
            acc1 = __builtin_amdgcn_mfma_f32_16x16x32_bf16(af, bf1, acc1, 0, 0, 0);
        }
        if (more) {
            unsigned short* dst = &Alds[buf ^ 1][lane * 4];
            unsigned short s[16];
            s[0]=f2bf(f0.x); s[1]=f2bf(f0.y); s[2]=f2bf(f0.z); s[3]=f2bf(f0.w);
            s[4]=f2bf(f1.x); s[5]=f2bf(f1.y); s[6]=f2bf(f1.z); s[7]=f2bf(f1.w);
            s[8]=f2bf(f2.x); s[9]=f2bf(f2.y); s[10]=f2bf(f2.z); s[11]=f2bf(f2.w);
            s[12]=f2bf(f3.x); s[13]=f2bf(f3.y); s[14]=f2bf(f3.z); s[15]=f2bf(f3.w);
            #pragma unroll
            for (int j = 0; j < 4; ++j) {
                int rr = wbr + 4 * j;
                *(uint2*)&dst[rr * LSTR] = *(uint2*)&s[j * 4];
            }
        }
        __syncthreads();
    }

    // epilogue: C[row = r0 + quad*4 + reg][col = (w*2+cc)*16 + ln]
    float* dst = partial + ((size_t)by * 3232 + r0 + quad * 4) * 128 + ln;
    #pragma unroll
    for (int reg = 0; reg < 4; ++reg) {
        dst[(size_t)reg * 128 + (w * 2 + 0) * 16] = acc0[reg];
        dst[(size_t)reg * 128 + (w * 2 + 1) * 16] = acc1[reg];
    }
}

// ---------------------------------------------------------------- reduce K-slices + tanh + mask
__global__ __launch_bounds__(128) void reduce_tanh(const float* __restrict__ partial,
                                                   float* __restrict__ xe,
                                                   float* __restrict__ ae,
                                                   float* __restrict__ maskg) {
    int row = blockIdx.x;   // 0..3231
    int e = threadIdx.x;
    float s = 0.f;
    #pragma unroll
    for (int k = 0; k < KS; ++k)
        s += partial[((size_t)k * 3232 + row) * 128 + e];
    float v = fast_tanh(s);
    if (row < 3200) {
        xe[(size_t)row * 128 + e] = v;
        __shared__ int any;
        if (e == 0) any = 0;
        __syncthreads();
        if (v != 0.f) any = 1;
        __syncthreads();
        if (e == 0) maskg[row] = any ? 1.f : 0.f;
    } else {
        ae[(row - 3200) * 128 + e] = v;
    }
}

// ---------------------------------------------------------------- x_proj = xe @ gru_k + b_i   [3200][384]
__global__ __launch_bounds__(384) void xproj_kernel(const float* __restrict__ xe,
                                                    const float* __restrict__ gru_k,
                                                    const float* __restrict__ b_i,
                                                    float* __restrict__ xproj) {
    __shared__ float xs[16 * 128];
    int tid = threadIdx.x;
    int row0 = blockIdx.x * 16;
    const float4v* src = (const float4v*)(xe + (size_t)row0 * 128);
    float4v* dstl = (float4v*)xs;
    #pragma unroll
    for (int c = 0; c < 2; ++c) {
        int i4 = c * 384 + tid;
        if (i4 < 512) dstl[i4] = src[i4];
    }
    __syncthreads();
    int j = tid;  // 0..383
    float acc[16];
    #pragma unroll
    for (int r = 0; r < 16; ++r) acc[r] = 0.f;
    float bi = b_i[j];
    for (int k4 = 0; k4 < 32; ++k4) {
        float g0 = gru_k[(k4 * 4 + 0) * 384 + j];
        float g1 = gru_k[(k4 * 4 + 1) * 384 + j];
        float g2 = gru_k[(k4 * 4 + 2) * 384 + j];
        float g3 = gru_k[(k4 * 4 + 3) * 384 + j];
        #pragma unroll
        for (int r = 0; r < 16; ++r) {
            float4v xv = *(const float4v*)&xs[r * 128 + k4 * 4];
            acc[r] = fmaf(xv.x, g0, acc[r]);
            acc[r] = fmaf(xv.y, g1, acc[r]);
            acc[r] = fmaf(xv.z, g2, acc[r]);
            acc[r] = fmaf(xv.w, g3, acc[r]);
        }
    }
    #pragma unroll
    for (int r = 0; r < 16; ++r)
        xproj[(size_t)(row0 + r) * 384 + j] = acc[r] + bi;
}

// ---------------------------------------------------------------- GRU scan: 1 block / batch
__global__ __launch_bounds__(384) void gru_kernel(const float* __restrict__ xproj,
                                                  const float* __restrict__ maskg,
                                                  const float* __restrict__ gru_rk,
                                                  const float* __restrict__ b_r,
                                                  float* __restrict__ hout) {
    int b = blockIdx.x;
    int j = threadIdx.x;  // 0..383
    float w[128];
    #pragma unroll
    for (int k = 0; k < 128; ++k) w[k] = gru_rk[k * 384 + j];
    float br = b_r[j];
    __shared__ float4v hs4[32];
    __shared__ float recs[384];
    float* hs = (float*)hs4;
    float hreg = 0.f;
    if (j < 128) hs[j] = 0.f;
    const float* xp_base = xproj + (size_t)b * 100 * 384;
    const float* mk = maskg + b * 100;
    float xz = 0.f, xr = 0.f, xh = 0.f;
    if (j < 128) { xz = xp_base[j]; xr = xp_base[128 + j]; xh = xp_base[256 + j]; }
    __syncthreads();
    for (int t = 0; t < 100; ++t) {
        float nxz = 0.f, nxr = 0.f, nxh = 0.f;
        if (t < 99 && j < 128) {
            const float* nb = xp_base + (t + 1) * 384;
            nxz = nb[j]; nxr = nb[128 + j]; nxh = nb[256 + j];
        }
        float s0 = 0.f, s1 = 0.f, s2 = 0.f, s3 = 0.f;
        #pragma unroll
        for (int k4 = 0; k4 < 32; ++k4) {
            float4v hv = hs4[k4];
            s0 = fmaf(hv.x, w[k4 * 4 + 0], s0);
            s1 = fmaf(hv.y, w[k4 * 4 + 1], s1);
            s2 = fmaf(hv.z, w[k4 * 4 + 2], s2);
            s3 = fmaf(hv.w, w[k4 * 4 + 3], s3);
        }
        recs[j] = br + ((s0 + s1) + (s2 + s3));
        __syncthreads();
        if (j < 128) {
            float z = sigmoidf_(xz + recs[j]);
            float r = sigmoidf_(xr + recs[128 + j]);
            float hh = fast_tanh(xh + r * recs[256 + j]);
            float hn = z * hreg + (1.f - z) * hh;
            hreg = (mk[t] != 0.f) ? hn : hreg;
            hs[j] = hreg;
        }
        __syncthreads();
        xz = nxz; xr = nxr; xh = nxh;
    }
    if (j < 128) hout[b * 128 + j] = hreg;
}

// ---------------------------------------------------------------- head
__global__ __launch_bounds__(64) void head_kernel(const float* __restrict__ hout,
                                                  const float* __restrict__ ae,
                                                  const float* __restrict__ d,
                                                  const float* __restrict__ W1,
                                                  const float* __restrict__ b1,
                                                  const float* __restrict__ W2,
                                                  const float* __restrict__ b2,
                                                  float* __restrict__ out) {
    int b = blockIdx.x;
    int m = threadIdx.x;  // 0..63
    float s = b1[m];
    const float* hb = hout + b * 128;
    const float* ab = ae + b * 128;
    #pragma unroll 4
    for (int k = 0; k < 128; ++k) s = fmaf(hb[k], W1[k * 64 + m], s);
    #pragma unroll 4
    for (int k = 0; k < 128; ++k) s = fmaf(ab[k], W1[(128 + k) * 64 + m], s);
    float c = fast_tanh(s);
    float p = c * W2[m];
    #pragma unroll
    for (int off = 32; off > 0; off >>= 1) p += __shfl_down(p, off);
    if (m == 0) {
        p += d[b * 2 + 0] * W2[64] + d[b * 2 + 1] * W2[65] + b2[0];
        out[b] = sigmoidf_(p);
    }
}

extern "C" void kernel_launch(void* const* d_in, const int* in_sizes, int n_in,
                              void* d_out, int out_size, void* d_ws, size_t ws_size,
                              hipStream_t stream) {
    (void)in_sizes; (void)n_in; (void)out_size; (void)ws_size;
    const float* x      = (const float*)d_in[0];
    const float* a      = (const float*)d_in[1];
    const float* d      = (const float*)d_in[2];
    const float* emb    = (const float*)d_in[3];
    const float* gru_k  = (const float*)d_in[4];
    const float* gru_rk = (const float*)d_in[5];
    const float* gbi    = (const float*)d_in[6];
    const float* gbr    = (const float*)d_in[7];
    const float* W1     = (const float*)d_in[8];
    const float* b1     = (const float*)d_in[9];
    const float* W2     = (const float*)d_in[10];
    const float* b2     = (const float*)d_in[11];
    float* out = (float*)d_out;

    char* ws = (char*)d_ws;
    unsigned short* embT = (unsigned short*)(ws);              //  5,120,000 B
    float* xe      = (float*)(ws + 5120000);                   //  1,638,400 B
    float* ae      = (float*)(ws + 6758400);                   //     16,384 B
    float* maskg   = (float*)(ws + 6774784);                   //     12,800 B
    float* xproj   = (float*)(ws + 6787584);                   //  4,915,200 B
    float* hout    = (float*)(ws + 11702784);                  //     16,384 B
    float* partial = (float*)(ws + 11719168);                  // 13,238,272 B (KS*3232*128*4)

    hipLaunchKernelGGL(cvt_embT,    dim3(313),      dim3(256), 0, stream, emb, embT);
    hipLaunchKernelGGL(big_gemm,    dim3(202, KS),  dim3(256), 0, stream, x, a, embT, partial);
    hipLaunchKernelGGL(reduce_tanh, dim3(3232),     dim3(128), 0, stream, partial, xe, ae, maskg);
    hipLaunchKernelGGL(xproj_kernel,dim3(200),      dim3(384), 0, stream, xe, gru_k, gbi, xproj);
    hipLaunchKernelGGL(gru_kernel,  dim3(32),       dim3(384), 0, stream, xproj, maskg, gru_rk, gbr, hout);
    hipLaunchKernelGGL(head_kernel, dim3(32),       dim3(64),  0, stream, hout, ae, d, W1, b1, W2, b2, out);
}